// Round 10
// baseline (61.238 us; speedup 1.0000x reference)
//
#include <hip/hip_runtime.h>
#include <cmath>

// QuanvolutionSelfAttentionClassifier on MI355X — round 10.
//
// Algebra (verified R1/R2/R5/R6/R7/R9): softmax over length-1 axis == 1 ->
// attn_weights == mean_embeds (rotation/entangle params dead). With
// l = c*196 + p, embedding index d = p & 3; for input pixel (r,cc):
// d = (2*((r>>1)&1) + (cc>>1)) & 3.
//   logits[j] = lin_b[j] + sum_d M[d] * (cst[d][j] + T[d][j])
//   M[d]    = a + sum_pix x[pix]*gm(pix),   a = sum_c conv_b[c]/4
//   T[d][j] = sum_{pix: d(pix)==d} x[pix] * G[pix][j]
//
// R9 evidence: L3-resident replays still took 67us (NOT HBM-bound); VALUBusy
// 20%; spill-free. Limiter: 28-barrier lockstep (tiny ~340cy compute between
// lgkmcnt(0)+s_barrier sync points, paid serially 28x at 2 blocks/CU) plus
// 4x-redundant row reads. v10: 4 ROWS PER BARRIER (7 super-steps, 8 barriers)
// over two [64][4][36+pad] planes (75.8KB dbuf); staging prefetched a full
// super-step ahead; rh-waves read only their needed half of each row (4 b128,
// stride-148 conflict-free). G via readlane (R9-verified layout), prefetched
// 4 rows ahead (GA/GB static). Compute & epilogue math identical to R9.

#define WS_A    9408
#define WS_CST  9409

__global__ void qsac_prep(const float* __restrict__ cw, const float* __restrict__ cb,
                          const float* __restrict__ lw, float* __restrict__ ws) {
  const int t = blockIdx.x * 98 + threadIdx.x;  // 8 x 98 = 784 pixels
  const int r = t / 28, cc = t - r * 28;
  const int kh = r & 1, kw = cc & 1;
  const int p = (r >> 1) * 14 + (cc >> 1);
  const float w0 = cw[(kh << 1) + kw],     w1 = cw[4 + (kh << 1) + kw],
              w2 = cw[8 + (kh << 1) + kw], w3 = cw[12 + (kh << 1) + kw];
  float g[10];
#pragma unroll
  for (int j = 0; j < 10; ++j)
    g[j] = w0 * lw[j * 784 + p]       + w1 * lw[j * 784 + 196 + p] +
           w2 * lw[j * 784 + 392 + p] + w3 * lw[j * 784 + 588 + p];
  const float gm = (w0 + w1 + w2 + w3) * (1.0f / 196.0f);
  // Layout: ws[ch*4704 + r*168 + pr*12 + e*6 + k]; k<5 -> j=ch*5+k, k=5 -> 0|gm.
  const int pr = cc >> 1, e = cc & 1;
  float* d0 = ws + r * 168 + pr * 12 + e * 6;
  d0[0] = g[0]; d0[1] = g[1]; d0[2] = g[2]; d0[3] = g[3]; d0[4] = g[4]; d0[5] = 0.f;
  float* d1 = ws + 4704 + r * 168 + pr * 12 + e * 6;
  d1[0] = g[5]; d1[1] = g[6]; d1[2] = g[7]; d1[3] = g[8]; d1[4] = g[9]; d1[5] = gm;

  if (blockIdx.x == 0) {
    const int u = threadIdx.x;
    if (u < 40) {
      const int d = u / 10, j = u - (u / 10) * 10;
      const float b0 = cb[0], b1 = cb[1], b2 = cb[2], b3 = cb[3];
      float s = 0.f;
#pragma unroll 7
      for (int q = d; q < 196; q += 4)
        s += b0 * lw[j * 784 + q]       + b1 * lw[j * 784 + 196 + q] +
             b2 * lw[j * 784 + 392 + q] + b3 * lw[j * 784 + 588 + q];
      ws[WS_CST + u] = s;
    } else if (u == 40) {
      ws[WS_A] = (cb[0] + cb[1] + cb[2] + cb[3]) * 0.25f;
    }
  }
}

#define BAR()                                            \
  asm volatile("s_waitcnt lgkmcnt(0)" ::: "memory");     \
  __builtin_amdgcn_s_barrier();                          \
  asm volatile("" ::: "memory");

// Broadcast float I of a row's G slice (per-lane float4 over lanes 0..41)
// into an SGPR: compile-time component select + v_readlane.
template <int I>
__device__ __forceinline__ float rl(const float4& v) {
  constexpr int c = I & 3;
  const float f = (c == 0) ? v.x : (c == 1) ? v.y : (c == 2) ? v.z : v.w;
  return __int_as_float(__builtin_amdgcn_readlane(__float_as_int(f), I >> 2));
}

// One pixel-pair P (global pair index; cols 2P,2P+1; shared d-class):
// 12 readlane + 12 fmac. OFS localizes the tr chunk index per rh half.
#define PAIRR(P, PAR, RR, OFS)                                                \
  {                                                                           \
    constexpr int DD = (2 * (PAR) + ((P)&3)) & 3;                             \
    const float xA =                                                          \
        (((P)&1) ? trs[((P) >> 1) - (OFS)].z : trs[((P) >> 1) - (OFS)].x);    \
    const float xB =                                                          \
        (((P)&1) ? trs[((P) >> 1) - (OFS)].w : trs[((P) >> 1) - (OFS)].y);    \
    acc[DD][0] += xA * rl<12 * (P) + 0>(GA[RR]);                              \
    acc[DD][1] += xA * rl<12 * (P) + 1>(GA[RR]);                              \
    acc[DD][2] += xA * rl<12 * (P) + 2>(GA[RR]);                              \
    acc[DD][3] += xA * rl<12 * (P) + 3>(GA[RR]);                              \
    acc[DD][4] += xA * rl<12 * (P) + 4>(GA[RR]);                              \
    acc[DD][5] += xA * rl<12 * (P) + 5>(GA[RR]);                              \
    acc[DD][0] += xB * rl<12 * (P) + 6>(GA[RR]);                              \
    acc[DD][1] += xB * rl<12 * (P) + 7>(GA[RR]);                              \
    acc[DD][2] += xB * rl<12 * (P) + 8>(GA[RR]);                              \
    acc[DD][3] += xB * rl<12 * (P) + 9>(GA[RR]);                              \
    acc[DD][4] += xB * rl<12 * (P) + 10>(GA[RR]);                             \
    acc[DD][5] += xB * rl<12 * (P) + 11>(GA[RR]);                             \
  }

// One row RR (0..3) of the current plane. PAR = (RR>>1)&1 is exact because
// absolute row = 4*ss + RR and (4ss)>>1 is even. Each rh-half reads only its
// 4 needed b128 chunks (cols 0-15 / 12-27).
#define ROW(RR, PAR)                                                          \
  {                                                                           \
    float4 trs[4];                                                            \
    _Pragma("unroll") for (int i = 0; i < 4; ++i)                             \
      trs[i] = *reinterpret_cast<const float4*>(pc + (RR)*36 + i * 4);        \
    if (rh == 0) {                                                            \
      PAIRR(0, PAR, RR, 0) PAIRR(1, PAR, RR, 0) PAIRR(2, PAR, RR, 0)          \
      PAIRR(3, PAR, RR, 0) PAIRR(4, PAR, RR, 0) PAIRR(5, PAR, RR, 0)          \
      PAIRR(6, PAR, RR, 0)                                                    \
    } else {                                                                  \
      PAIRR(7, PAR, RR, 3) PAIRR(8, PAR, RR, 3) PAIRR(9, PAR, RR, 3)          \
      PAIRR(10, PAR, RR, 3) PAIRR(11, PAR, RR, 3) PAIRR(12, PAR, RR, 3)       \
      PAIRR(13, PAR, RR, 3)                                                   \
    }                                                                         \
  }

#define PLANE_F 9472  // [64 samples][148] floats (4 rows x 36 + 4 pad)

__global__ __launch_bounds__(256)
__attribute__((amdgpu_waves_per_eu(2, 2))) void qsac_main(
    const float* __restrict__ x, const float* __restrict__ ws,
    const float* __restrict__ lin_b, float* __restrict__ out) {
  __shared__ float smem[2 * PLANE_F];  // 75,776 B double-buffered planes

  const int tid = threadIdx.x;
  const int lane = tid & 63;
  const int wid = __builtin_amdgcn_readfirstlane(tid >> 6);
  const int ch = wid >> 1, rh = wid & 1;
  const int sbase = blockIdx.x * 64;
  // Per-lane G slice: lane l<42 holds floats [4l,4l+4) of each 168-float row
  // of this wave's ch slice (lanes >=42 clamp, unused).
  const float* gsl = ws + ch * 4704 + ((lane < 42) ? lane * 4 : 0);

  // Staging decomposition: chunk c = tid + 256k (k=0..6) covers 1792 chunks =
  // 4 rows x 448 (64 samples x 7 float4). c -> row rr=c/448, sample s, m.
  int wadr[7];
  const float* xp[7];
#pragma unroll
  for (int k = 0; k < 7; ++k) {
    const int c = tid + k * 256;
    const int rr = c / 448, cc2 = c - rr * 448;
    const int s = cc2 / 7, m = cc2 - s * 7;
    wadr[k] = s * 148 + rr * 36 + m * 4;
    xp[k] = x + (size_t)(sbase + s) * 784 + rr * 28 + m * 4;
  }

  // Prologue: SS0 rows -> plane0; SS1 rows -> R; G rows 0-3 -> GA.
  float4 R[7], GA[4], GB[4];
#pragma unroll
  for (int k = 0; k < 7; ++k) R[k] = *reinterpret_cast<const float4*>(xp[k]);
#pragma unroll
  for (int k = 0; k < 7; ++k)
    *reinterpret_cast<float4*>(smem + wadr[k]) = R[k];
#pragma unroll
  for (int k = 0; k < 7; ++k)
    R[k] = *reinterpret_cast<const float4*>(xp[k] + 112);
#pragma unroll
  for (int rr = 0; rr < 4; ++rr)
    GA[rr] = *reinterpret_cast<const float4*>(gsl + rr * 168);
  BAR()

  float acc[4][6];
#pragma unroll
  for (int d = 0; d < 4; ++d)
#pragma unroll
    for (int q = 0; q < 6; ++q) acc[d][q] = 0.f;

  const int rdbase = lane * 148 + rh * 12;

  // 7 super-steps of 4 rows; ONE barrier each. Writes of plane (ss+1)&1 are
  // WAR-safe: its readers (super-step ss-1) drained at the previous BAR.
#pragma unroll 1
  for (int ss = 0; ss < 7; ++ss) {
    if (ss < 6) {
      float* wp = smem + ((ss + 1) & 1) * PLANE_F;
#pragma unroll
      for (int k = 0; k < 7; ++k)
        *reinterpret_cast<float4*>(wp + wadr[k]) = R[k];
      if (ss < 5) {
#pragma unroll
        for (int k = 0; k < 7; ++k)
          R[k] = *reinterpret_cast<const float4*>(xp[k] + (ss + 2) * 112);
      }
#pragma unroll
      for (int rr = 0; rr < 4; ++rr)
        GB[rr] = *reinterpret_cast<const float4*>(gsl + (4 * (ss + 1) + rr) * 168);
    }
    const float* pc = smem + (ss & 1) * PLANE_F + rdbase;
    ROW(0, 0) ROW(1, 0) ROW(2, 1) ROW(3, 1)
    if (ss < 6) {
#pragma unroll
      for (int rr = 0; rr < 4; ++rr) GA[rr] = GB[rr];
    }
    BAR()
  }

  // ---- epilogue (R9-verified; planes dead — overlay Red [0,3072) /
  // Mld [3072,3328) / L [3328,4096)). rh-reduction sums pair-split partials.
  if (rh == 1) {
    float* rd = smem + ch * 1536 + lane * 24;
#pragma unroll
    for (int d = 0; d < 4; ++d)
#pragma unroll
      for (int q = 0; q < 6; ++q) rd[d * 6 + q] = acc[d][q];
  }
  __syncthreads();
  if (rh == 0) {
    const float* rd = smem + ch * 1536 + lane * 24;
#pragma unroll
    for (int d = 0; d < 4; ++d)
#pragma unroll
      for (int q = 0; q < 6; ++q) acc[d][q] += rd[d * 6 + q];
  }
  if (wid == 2) {  // ch1, rh0: full mean sums in slot 5 after reduction
    const float a = ws[WS_A];
#pragma unroll
    for (int d = 0; d < 4; ++d) smem[3072 + lane * 4 + d] = a + acc[d][5];
  }
  __syncthreads();
  if (rh == 0) {
    float M[4];
#pragma unroll
    for (int d = 0; d < 4; ++d) M[d] = smem[3072 + lane * 4 + d];
#pragma unroll
    for (int q = 0; q < 5; ++q) {
      const int j = ch * 5 + q;
      float v = lin_b[j];
#pragma unroll
      for (int d = 0; d < 4; ++d)
        v += M[d] * (ws[WS_CST + d * 10 + j] + acc[d][q]);
      smem[3328 + lane * 12 + j] = v;
    }
  }
  __syncthreads();
  if (wid == 0) {
    float logits[10];
#pragma unroll
    for (int j = 0; j < 10; ++j) logits[j] = smem[3328 + lane * 12 + j];
    float mx = logits[0];
#pragma unroll
    for (int j = 1; j < 10; ++j) mx = fmaxf(mx, logits[j]);
    float se = 0.f;
#pragma unroll
    for (int j = 0; j < 10; ++j) se += __expf(logits[j] - mx);
    const float lse = mx + __logf(se);
    float* op = out + (size_t)(sbase + lane) * 10;
#pragma unroll
    for (int j = 0; j < 10; ++j) op[j] = logits[j] - lse;
  }
}

extern "C" void kernel_launch(void* const* d_in, const int* in_sizes, int n_in,
                              void* d_out, int out_size, void* d_ws, size_t ws_size,
                              hipStream_t stream) {
  (void)n_in; (void)ws_size; (void)out_size;
  const float* x = (const float*)d_in[0];
  const float* conv_w = (const float*)d_in[1];
  const float* conv_b = (const float*)d_in[2];
  // d_in[3]/d_in[4] (rotation/entangle) are dead: softmax over length-1 == 1.
  const float* lin_w = (const float*)d_in[5];
  const float* lin_b = (const float*)d_in[6];
  float* out = (float*)d_out;
  float* ws = (float*)d_ws;

  hipLaunchKernelGGL(qsac_prep, dim3(8), dim3(98), 0, stream,
                     conv_w, conv_b, lin_w, ws);

  const int B = in_sizes[0] / 784;  // 32768
  const int nblk = B / 64;          // 512 blocks x 256 threads
  hipLaunchKernelGGL(qsac_main, dim3(nblk), dim3(256), 0, stream,
                     x, ws, lin_b, out);
}

// Round 11
// 60.533 us; speedup vs baseline: 1.0116x; 1.0116x over previous
//
#include <hip/hip_runtime.h>

// QuanvolutionSelfAttentionClassifier on MI355X — round 11: MFMA rewrite.
//
// Algebra (verified R1-R10): softmax over length-1 axis == 1 ->
// attn_weights == mean_embeds (rotation/entangle params dead). With
// l = c*196 + p, embedding index d = p & 3; pixel (r,cc):
// d = (2*((r>>1)&1) + (cc>>1)) & 3.
//   logits[j] = lin_b[j] + sum_d M[d] * (cst[d][j] + T[d][j])
//   M[d]    = a + sum_pix x[pix]*gm(pix),   a = sum_c conv_b[c]/4
//   T[d][j] = sum_{pix: d(pix)==d} x[pix] * G[pix][j]
//
// 10 rounds of f32-VALU designs all hit the same wall: ~44 accumulators +
// staging regs/thread -> RA spills (R1/R2/R3/R5/R10) or 20%-VALUBusy
// dependency stalls (R7/R9). But Y[64][44] = X[64][784]·G[784][44] is
// matmul-shaped -> use the matrix pipe (Guideline 10):
//  - G split to bf16 hi/lo planes Gt[48 cols][896 k] (prep; split-bf16 ~16
//    mantissa bits; logit err ~1e-4 << 7.8e-2 threshold). col = d*12 + j,
//    mu-weight at d*12+10, pads zero. K padded 784->896 with zeros.
//  - x staged f32 by global_load_lds (NO staging registers -> the chronic
//    spill source is deleted) into 2x32KB dbuf planes [64][128]; source
//    addresses pre-swizzled (chunk XOR sample) so the compute-side
//    ds_read_b128 is bank-uniform (m104/m231: swizzle source+read, dest linear).
//  - per K-step: read 8 f32, convert to hi/lo bf16x8 (~40 VALU), 9 MFMA
//    (3 n-tiles x {AhBh, AlBh, AhBl}) into 3 persistent f32x4 accs.
//    A/B k-placement built symmetrically (both use kb=lane>>4, 8 contiguous)
//    so any HW k-permutation cancels in the dot product; C layout is the
//    m89-verified col=lane&15, row=(lane>>4)*4+reg.
//  - 7 tiles, one __syncthreads each (its vmcnt(0) drain IS the intended
//    BW-matched pipeline: tile t+1 loads issued at tile-t start).
// Live regs ~55 -> below every observed spill threshold.

typedef __attribute__((ext_vector_type(8))) short bf16x8;
typedef __attribute__((ext_vector_type(4))) float f32x4;
typedef __attribute__((ext_vector_type(4))) unsigned int uint4v;

union BU { uint4v u; bf16x8 b; };

__device__ __forceinline__ unsigned short f2bf(float f) {
  unsigned u = __float_as_uint(f);
  unsigned r = u + 0x7FFFu + ((u >> 16) & 1u);
  return (unsigned short)(r >> 16);
}

#define CST_F  43008   // float idx in ws: cst[40]
#define A_F    43048   // float idx: a
#define ZERO_F 43056   // float idx: 16 zero floats (16B-aligned)

__global__ void qsac_prep(const float* __restrict__ cw, const float* __restrict__ cb,
                          const float* __restrict__ lw, float* __restrict__ wsf) {
  unsigned short* gt = (unsigned short*)wsf;  // Gt_hi [48][896], Gt_lo at +43008
  const int t = blockIdx.x * 256 + threadIdx.x;  // 168*256 = 43008 = 48*896
  const int col = t / 896, k = t - col * 896;
  float val = 0.f;
  if (k < 784) {
    const int r = k / 28, cc = k - r * 28;
    const int kh = r & 1, kw = cc & 1;
    const int p = (r >> 1) * 14 + (cc >> 1);
    const int dpix = (2 * ((r >> 1) & 1) + (cc >> 1)) & 3;
    const int cd = col / 12, cj = col - cd * 12;
    if (cd == dpix) {
      const float w0 = cw[(kh << 1) + kw],     w1 = cw[4 + (kh << 1) + kw],
                  w2 = cw[8 + (kh << 1) + kw], w3 = cw[12 + (kh << 1) + kw];
      if (cj < 10)
        val = w0 * lw[cj * 784 + p]       + w1 * lw[cj * 784 + 196 + p] +
              w2 * lw[cj * 784 + 392 + p] + w3 * lw[cj * 784 + 588 + p];
      else if (cj == 10)
        val = (w0 + w1 + w2 + w3) * (1.0f / 196.0f);
    }
  }
  const unsigned short hh = f2bf(val);
  const float hf = __uint_as_float((unsigned)hh << 16);
  gt[col * 896 + k] = hh;
  gt[43008 + col * 896 + k] = f2bf(val - hf);

  if (blockIdx.x == 0) {
    const int u = threadIdx.x;
    if (u < 40) {
      const int d = u / 10, j = u - (u / 10) * 10;
      const float b0 = cb[0], b1 = cb[1], b2 = cb[2], b3 = cb[3];
      float s = 0.f;
#pragma unroll 7
      for (int q = d; q < 196; q += 4)
        s += b0 * lw[j * 784 + q]       + b1 * lw[j * 784 + 196 + q] +
             b2 * lw[j * 784 + 392 + q] + b3 * lw[j * 784 + 588 + q];
      wsf[CST_F + u] = s;
    } else if (u == 40) {
      wsf[A_F] = (cb[0] + cb[1] + cb[2] + cb[3]) * 0.25f;
    } else if (u >= 48 && u < 64) {
      wsf[ZERO_F + (u - 48)] = 0.f;
    }
  }
}

__global__ __launch_bounds__(256)
__attribute__((amdgpu_waves_per_eu(2, 2))) void qsac_main(
    const float* __restrict__ x, const unsigned short* __restrict__ gt,
    const float* __restrict__ wsf, const float* __restrict__ lin_b,
    float* __restrict__ out) {
  __shared__ float smem[2 * 8192];  // two [64][128] f32 x-planes (64 KB)

  const int tid = threadIdx.x;
  const int lane = tid & 63;
  const int wid = __builtin_amdgcn_readfirstlane(tid >> 6);
  const int sbase = blockIdx.x * 64;
  const int nn = lane & 15;        // n within tile / m within tile
  const int kb = lane >> 4;        // k-block 0..3
  const int srow = wid * 16 + nn;  // this lane's A-row (sample)
  const int sw = srow & 31;        // read-side XOR swizzle key

  // Staging: chunk c = wid*512 + i*64 + lane; sample s = c>>5; physical
  // 16B-slot physm = c&31 holds logical slot mlog = physm ^ (s&31).
  int soff[8];
  int zmask = 0;
  const int hl = lane >> 5;
#pragma unroll
  for (int i = 0; i < 8; ++i) {
    const int s = wid * 16 + i * 2 + hl;
    const int mlog = (lane & 31) ^ (s & 31);
    soff[i] = (sbase + s) * 784 + mlog * 4;
    zmask |= (mlog >= 4) << i;  // tile 6: k = 768 + mlog*4 >= 784 -> zeros
  }

  f32x4 acc[3];
#pragma unroll
  for (int nt = 0; nt < 3; ++nt) acc[nt] = (f32x4){0.f, 0.f, 0.f, 0.f};

  auto stage = [&](int tile, int buf) {
    const bool last = (tile == 6);
#pragma unroll
    for (int i = 0; i < 8; ++i) {
      const float* src = x + (soff[i] + tile * 128);
      if (last && ((zmask >> i) & 1)) src = wsf + ZERO_F;
      __builtin_amdgcn_global_load_lds(
          (const __attribute__((address_space(1))) unsigned int*)src,
          (__attribute__((address_space(3))) unsigned int*)
              &smem[buf * 8192 + wid * 2048 + i * 256],
          16, 0, 0);
    }
  };

  stage(0, 0);
  __syncthreads();

#pragma unroll 1
  for (int t = 0; t < 7; ++t) {
    if (t < 6) stage(t + 1, (t + 1) & 1);
    const float* arow = &smem[(t & 1) * 8192 + srow * 128];
#pragma unroll
    for (int ks = 0; ks < 4; ++ks) {
      const int l0 = ks * 8 + kb * 2;  // logical 16B chunk of this lane's 8 k
      const float4 xa = *(const float4*)&arow[(l0 ^ sw) * 4];
      const float4 xb = *(const float4*)&arow[((l0 + 1) ^ sw) * 4];
      const float v[8] = {xa.x, xa.y, xa.z, xa.w, xb.x, xb.y, xb.z, xb.w};
      bf16x8 Ah, Al;
#pragma unroll
      for (int e = 0; e < 8; ++e) {
        const unsigned short hh = f2bf(v[e]);
        Ah[e] = (short)hh;
        Al[e] = (short)f2bf(v[e] - __uint_as_float((unsigned)hh << 16));
      }
      const int kglob = t * 128 + ks * 32 + kb * 8;
#pragma unroll
      for (int nt = 0; nt < 3; ++nt) {
        const int gidx = (nt * 16 + nn) * 896 + kglob;
        BU bh, bl;
        bh.u = *(const uint4v*)(gt + gidx);
        bl.u = *(const uint4v*)(gt + 43008 + gidx);
        acc[nt] = __builtin_amdgcn_mfma_f32_16x16x32_bf16(Ah, bh.b, acc[nt], 0, 0, 0);
        acc[nt] = __builtin_amdgcn_mfma_f32_16x16x32_bf16(Al, bh.b, acc[nt], 0, 0, 0);
        acc[nt] = __builtin_amdgcn_mfma_f32_16x16x32_bf16(Ah, bl.b, acc[nt], 0, 0, 0);
      }
    }
    __syncthreads();  // drains vmcnt -> tile t+1 staged; WAR-safe dbuf swap
  }

  // ---- epilogue: C -> LDS [64][52], then 64 lanes finish per-sample ----
  float* cx = smem;  // planes dead after final barrier
#pragma unroll
  for (int nt = 0; nt < 3; ++nt)
#pragma unroll
    for (int rg = 0; rg < 4; ++rg)
      cx[(wid * 16 + (lane >> 4) * 4 + rg) * 52 + nt * 16 + nn] = acc[nt][rg];
  __syncthreads();

  if (tid < 64) {
    const int s = tid;
    float Y[48];
#pragma unroll
    for (int q = 0; q < 12; ++q) {
      const float4 t4 = *(const float4*)&cx[s * 52 + q * 4];
      Y[q * 4 + 0] = t4.x; Y[q * 4 + 1] = t4.y;
      Y[q * 4 + 2] = t4.z; Y[q * 4 + 3] = t4.w;
    }
    const float a = wsf[A_F];
    float M[4];
#pragma unroll
    for (int d = 0; d < 4; ++d) M[d] = a + Y[d * 12 + 10];
    float logits[10];
#pragma unroll
    for (int j = 0; j < 10; ++j) {
      float vv = lin_b[j];
#pragma unroll
      for (int d = 0; d < 4; ++d)
        vv += M[d] * (wsf[CST_F + d * 10 + j] + Y[d * 12 + j]);
      logits[j] = vv;
    }
    float mx = logits[0];
#pragma unroll
    for (int j = 1; j < 10; ++j) mx = fmaxf(mx, logits[j]);
    float se = 0.f;
#pragma unroll
    for (int j = 0; j < 10; ++j) se += __expf(logits[j] - mx);
    const float lse = mx + __logf(se);
    float* op = out + (size_t)(sbase + s) * 10;
#pragma unroll
    for (int j = 0; j < 10; ++j) op[j] = logits[j] - lse;
  }
}

extern "C" void kernel_launch(void* const* d_in, const int* in_sizes, int n_in,
                              void* d_out, int out_size, void* d_ws, size_t ws_size,
                              hipStream_t stream) {
  (void)n_in; (void)ws_size; (void)out_size;
  const float* x = (const float*)d_in[0];
  const float* conv_w = (const float*)d_in[1];
  const float* conv_b = (const float*)d_in[2];
  // d_in[3]/d_in[4] (rotation/entangle) are dead: softmax over length-1 == 1.
  const float* lin_w = (const float*)d_in[5];
  const float* lin_b = (const float*)d_in[6];
  float* out = (float*)d_out;
  float* wsf = (float*)d_ws;

  hipLaunchKernelGGL(qsac_prep, dim3(168), dim3(256), 0, stream,
                     conv_w, conv_b, lin_w, wsf);

  const int B = in_sizes[0] / 784;  // 32768
  const int nblk = B / 64;          // 512 blocks x 256 threads
  hipLaunchKernelGGL(qsac_main, dim3(nblk), dim3(256), 0, stream,
                     x, (const unsigned short*)wsf, wsf, lin_b, out);
}

// Round 12
// 43.861 us; speedup vs baseline: 1.3962x; 1.3801x over previous
//
#include <hip/hip_runtime.h>

// QuanvolutionSelfAttentionClassifier on MI355X — round 12: barrier-free MFMA.
//
// Algebra (verified R1-R11): softmax over length-1 axis == 1 ->
// attn_weights == mean_embeds (rotation/entangle dead). l = c*196+p ->
// d = p&3; pixel (r,cc): d = (2*((r>>1)&1) + (cc>>1)) & 3.
//   logits[j] = lin_b[j] + sum_d M[d]*(cst[d][j] + T[d][j])
//   M[d] = a + sum_pix x*gm,  T[d][j] = sum_{pix in d} x*G[pix][j]
// Y[64][48] = X[64][784]·G[784][48] via mfma_f32_16x16x32_bf16, split-bf16
// hi/lo (3 MFMA: AhBh+AlBh+AhBl), col = d*12+j (10 logits, mu at +10, pad).
// A/B k-placement symmetric (kb=lane>>4, 8 contiguous k) -> HW k-permutation
// cancels; C layout col=lane&15,row=(lane>>4)*4+reg — ALL verified in R11
// (absmax 0.0156 = f32 rounds' floor).
//
// R11 diagnosis: L3-resident replays still 69us; MfmaUtil 4.4%, VALUBusy 11%
// -> all pipes idle. Shared cause across R7-R11: barrier-locked stage
// pipeline at 2 blocks/CU — every __syncthreads drains vmcnt(0) on the
// just-issued next-tile global_load_lds (m97 stall), serializing the full
// memory latency per tile with no independent waves to hide it.
// v12: NO LDS staging, NO barriers. A-fragment loads x DIRECTLY: per k-step
// lane reads 32B contiguous of row (lane&15); rows 64B-aligned; the 4
// kb-lanes cover 128B = 2 full lines (zero over-fetch, pure stream).
// Each wave owns 16 samples independently; B (G, K-padded to 800, zeros)
// is L2-resident. waves_per_eu(4,4): 16 independent waves/CU hide latency
// by TLP. Live regs ~70 < 128 budget (no spill). Epilogue wave-private.

typedef __attribute__((ext_vector_type(8))) short bf16x8;
typedef __attribute__((ext_vector_type(4))) float f32x4;
typedef __attribute__((ext_vector_type(4))) unsigned int uint4v;

union BU { uint4v u; bf16x8 b; };

__device__ __forceinline__ unsigned short f2bf(float f) {
  unsigned u = __float_as_uint(f);
  unsigned r = u + 0x7FFFu + ((u >> 16) & 1u);
  return (unsigned short)(r >> 16);
}

#define GLO_S 38400   // short idx of lo-plane; hi at [0,38400) = 48 cols x 800 k
#define CST_F 38400   // float idx: cst[40] (after 76800 shorts = 38400 floats)
#define A_F   38440   // float idx: a

__global__ void qsac_prep(const float* __restrict__ cw, const float* __restrict__ cb,
                          const float* __restrict__ lw, float* __restrict__ wsf) {
  unsigned short* gt = (unsigned short*)wsf;
  const int t = blockIdx.x * 256 + threadIdx.x;  // 150*256 = 38400 = 48*800
  const int col = t / 800, k = t - col * 800;
  float val = 0.f;
  if (k < 784) {
    const int r = k / 28, cc = k - r * 28;
    const int kh = r & 1, kw = cc & 1;
    const int p = (r >> 1) * 14 + (cc >> 1);
    const int dpix = (2 * ((r >> 1) & 1) + (cc >> 1)) & 3;
    const int cd = col / 12, cj = col - cd * 12;
    if (cd == dpix) {
      const float w0 = cw[(kh << 1) + kw],     w1 = cw[4 + (kh << 1) + kw],
                  w2 = cw[8 + (kh << 1) + kw], w3 = cw[12 + (kh << 1) + kw];
      if (cj < 10)
        val = w0 * lw[cj * 784 + p]       + w1 * lw[cj * 784 + 196 + p] +
              w2 * lw[cj * 784 + 392 + p] + w3 * lw[cj * 784 + 588 + p];
      else if (cj == 10)
        val = (w0 + w1 + w2 + w3) * (1.0f / 196.0f);
    }
  }
  const unsigned short hh = f2bf(val);
  const float hf = __uint_as_float((unsigned)hh << 16);
  gt[col * 800 + k] = hh;
  gt[GLO_S + col * 800 + k] = f2bf(val - hf);

  if (blockIdx.x == 0) {
    const int u = threadIdx.x;
    if (u < 40) {
      const int d = u / 10, j = u - (u / 10) * 10;
      const float b0 = cb[0], b1 = cb[1], b2 = cb[2], b3 = cb[3];
      float s = 0.f;
#pragma unroll 7
      for (int q = d; q < 196; q += 4)
        s += b0 * lw[j * 784 + q]       + b1 * lw[j * 784 + 196 + q] +
             b2 * lw[j * 784 + 392 + q] + b3 * lw[j * 784 + 588 + q];
      wsf[CST_F + u] = s;
    } else if (u == 40) {
      wsf[A_F] = (cb[0] + cb[1] + cb[2] + cb[3]) * 0.25f;
    }
  }
}

__global__ __launch_bounds__(256)
__attribute__((amdgpu_waves_per_eu(4, 4))) void qsac_main(
    const float* __restrict__ x, const unsigned short* __restrict__ gt,
    const float* __restrict__ wsf, const float* __restrict__ lin_b,
    float* __restrict__ out) {
  __shared__ float cx[4 * 16 * 52];  // 13.3 KB: per-wave C exchange [16][52]

  const int tid = threadIdx.x;
  const int lane = tid & 63;
  const int wid = __builtin_amdgcn_readfirstlane(tid >> 6);
  const int nn = lane & 15;   // A-row (sample-in-strip) AND B-col-in-tile
  const int kb = lane >> 4;   // k-block: 8 contiguous k at kb*8
  const int strip = blockIdx.x * 4 + wid;          // 16-sample strip, no
  const float* xrow = x + (size_t)(strip * 16 + nn) * 784;  // inter-wave ties

  f32x4 acc[3];
#pragma unroll
  for (int nt = 0; nt < 3; ++nt) acc[nt] = (f32x4){0.f, 0.f, 0.f, 0.f};

  // Depth-1 register prefetch of the 32B x chunk. Tail (t=24) clamps the
  // address for kb>=2 (k>=784): G rows 784..799 are zero, so the product is
  // zero regardless of the clamped values.
  float4 xa = *(const float4*)(xrow + kb * 8);
  float4 xb = *(const float4*)(xrow + kb * 8 + 4);

#pragma unroll 1
  for (int t = 0; t < 25; ++t) {
    float4 na = xa, nb = xb;
    if (t < 24) {
      const int ka = (t + 1) * 32 + kb * 8;
      const int kc = (ka < 784) ? ka : 0;
      na = *(const float4*)(xrow + kc);
      nb = *(const float4*)(xrow + kc + 4);
    }
    const float v[8] = {xa.x, xa.y, xa.z, xa.w, xb.x, xb.y, xb.z, xb.w};
    bf16x8 Ah, Al;
#pragma unroll
    for (int e = 0; e < 8; ++e) {
      const unsigned short hh = f2bf(v[e]);
      Ah[e] = (short)hh;
      Al[e] = (short)f2bf(v[e] - __uint_as_float((unsigned)hh << 16));
    }
    const int kg = t * 32 + kb * 8;
#pragma unroll
    for (int nt = 0; nt < 3; ++nt) {
      const int gidx = (nt * 16 + nn) * 800 + kg;
      BU bh, bl;
      bh.u = *(const uint4v*)(gt + gidx);
      bl.u = *(const uint4v*)(gt + GLO_S + gidx);
      acc[nt] = __builtin_amdgcn_mfma_f32_16x16x32_bf16(Ah, bh.b, acc[nt], 0, 0, 0);
      acc[nt] = __builtin_amdgcn_mfma_f32_16x16x32_bf16(Al, bh.b, acc[nt], 0, 0, 0);
      acc[nt] = __builtin_amdgcn_mfma_f32_16x16x32_bf16(Ah, bl.b, acc[nt], 0, 0, 0);
    }
    xa = na; xb = nb;
  }

  // ---- epilogue: wave-private C exchange, then lanes 0-15 finish ----
  float* mycx = cx + wid * (16 * 52);
#pragma unroll
  for (int nt = 0; nt < 3; ++nt)
#pragma unroll
    for (int rg = 0; rg < 4; ++rg)
      mycx[(kb * 4 + rg) * 52 + nt * 16 + nn] = acc[nt][rg];
  __builtin_amdgcn_wave_barrier();  // same-wave LDS pipe is in-order

  if (lane < 16) {
    float Y[48];
#pragma unroll
    for (int q = 0; q < 12; ++q) {
      const float4 t4 = *(const float4*)&mycx[lane * 52 + q * 4];
      Y[q * 4 + 0] = t4.x; Y[q * 4 + 1] = t4.y;
      Y[q * 4 + 2] = t4.z; Y[q * 4 + 3] = t4.w;
    }
    const float a = wsf[A_F];
    float M[4];
#pragma unroll
    for (int d = 0; d < 4; ++d) M[d] = a + Y[d * 12 + 10];
    float logits[10];
#pragma unroll
    for (int j = 0; j < 10; ++j) {
      float vv = lin_b[j];
#pragma unroll
      for (int d = 0; d < 4; ++d)
        vv += M[d] * (wsf[CST_F + d * 10 + j] + Y[d * 12 + j]);
      logits[j] = vv;
    }
    float mx = logits[0];
#pragma unroll
    for (int j = 1; j < 10; ++j) mx = fmaxf(mx, logits[j]);
    float se = 0.f;
#pragma unroll
    for (int j = 0; j < 10; ++j) se += __expf(logits[j] - mx);
    const float lse = mx + __logf(se);
    float* op = out + (size_t)(strip * 16 + lane) * 10;
#pragma unroll
    for (int j = 0; j < 10; ++j) op[j] = logits[j] - lse;
  }
}

extern "C" void kernel_launch(void* const* d_in, const int* in_sizes, int n_in,
                              void* d_out, int out_size, void* d_ws, size_t ws_size,
                              hipStream_t stream) {
  (void)n_in; (void)ws_size; (void)out_size;
  const float* x = (const float*)d_in[0];
  const float* conv_w = (const float*)d_in[1];
  const float* conv_b = (const float*)d_in[2];
  // d_in[3]/d_in[4] (rotation/entangle) are dead: softmax over length-1 == 1.
  const float* lin_w = (const float*)d_in[5];
  const float* lin_b = (const float*)d_in[6];
  float* out = (float*)d_out;
  float* wsf = (float*)d_ws;

  hipLaunchKernelGGL(qsac_prep, dim3(150), dim3(256), 0, stream,
                     conv_w, conv_b, lin_w, wsf);

  const int B = in_sizes[0] / 784;  // 32768
  const int nblk = B / 64;          // 512 blocks x 4 waves x 16 samples
  hipLaunchKernelGGL(qsac_main, dim3(nblk), dim3(256), 0, stream,
                     x, (const unsigned short*)wsf, wsf, lin_b, out);
}

// Round 13
// 31.273 us; speedup vs baseline: 1.9582x; 1.4025x over previous
//
#include <hip/hip_runtime.h>

// QuanvolutionSelfAttentionClassifier on MI355X — round 13: LDS-resident B.
//
// Algebra (verified R1-R12): softmax over length-1 axis == 1 ->
// attn_weights == mean_embeds (rotation/entangle dead). l = c*196+p ->
// d = p&3; pixel (r,cc): d = (2*((r>>1)&1) + (cc>>1)) & 3.
//   logits[j] = lin_b[j] + sum_d M[d]*(cst[d][j] + T[d][j])
//   M[d] = a + sum_pix x*gm,  T[d][j] = sum_{pix in d} x*G[pix][j]
// Y[samples][48] = X[.][784]·G[784][48] via mfma_f32_16x16x32_bf16 with
// split-bf16 hi/lo (AhBh+AlBh+AhBl), col = d*12+j; A/B k-placement symmetric
// (kb=lane>>4, 8 contiguous k); C layout col=lane&15,row=(lane>>4)*4+reg —
// numerics verified twice (R11/R12 absmax 0.0156 = the harness floor).
//
// R12 diagnosis: L3-resident == HBM-cold duration at 10-18% pipe util ->
// bound by per-CU L1/TA address processing, dominated by B-fragment global
// gathers (6 instr x 16 miss-lines per iter per wave; 19,200 miss-lines/CU).
// v13: B staged ONCE per CU into LDS (153.6 KB, fits the 160 KB gfx950
// workgroup limit; guide: 128 KB static verified in m201 example, 77.8 KB in
// our R8). 256 blocks x 512 threads (8 waves x 16 samples, 1 block/CU).
// Main loop: ZERO barriers; depth-1 ping-pong prefetch of A (2 global 16B
// loads — the only L1 traffic) and B (6 conflict-free ds_read_b128, separate
// LDS pipe). prep emits G fragment-major f32 (154 KB ws, under proven
// budget); staging splits to hi/lo bf16 with coalesced conflict-free writes.

typedef __attribute__((ext_vector_type(8))) short bf16x8;
typedef __attribute__((ext_vector_type(4))) float f32x4;
typedef __attribute__((ext_vector_type(4))) unsigned int uint4v;

union BU { uint4v u; bf16x8 b; };

__device__ __forceinline__ unsigned short f2bf(float f) {
  unsigned u = __float_as_uint(f);
  unsigned r = u + 0x7FFFu + ((u >> 16) & 1u);
  return (unsigned short)(r >> 16);
}
__device__ __forceinline__ float bf2f(unsigned short h) {
  return __uint_as_float((unsigned)h << 16);
}

#define CST_F 38400   // float idx in ws: cst[40]
#define A_F   38440   // float idx: a

// prep: G in fragment-major f32. f32 index i: e=i&7, lane=(i>>3)&63, c=i>>9;
// t=c/3, nt=c%3; nn=lane&15, kb=lane>>4; col=nt*16+nn; k=t*32+kb*8+e.
__global__ void qsac_prep(const float* __restrict__ cw, const float* __restrict__ cb,
                          const float* __restrict__ lw, float* __restrict__ wsf) {
  const int i = blockIdx.x * 256 + threadIdx.x;  // 150 blocks x 256 = 38400
  const int e = i & 7, lane = (i >> 3) & 63, c = i >> 9;
  const int t = c / 3, nt = c - t * 3;
  const int nn = lane & 15, kb = lane >> 4;
  const int col = nt * 16 + nn;
  const int k = t * 32 + kb * 8 + e;
  float val = 0.f;
  if (k < 784) {
    const int r = k / 28, cc = k - r * 28;
    const int kh = r & 1, kw = cc & 1;
    const int p = (r >> 1) * 14 + (cc >> 1);
    const int dpix = (2 * ((r >> 1) & 1) + (cc >> 1)) & 3;
    const int cd = col / 12, cj = col - cd * 12;
    if (cd == dpix) {
      const float w0 = cw[(kh << 1) + kw],     w1 = cw[4 + (kh << 1) + kw],
                  w2 = cw[8 + (kh << 1) + kw], w3 = cw[12 + (kh << 1) + kw];
      if (cj < 10)
        val = w0 * lw[cj * 784 + p]       + w1 * lw[cj * 784 + 196 + p] +
              w2 * lw[cj * 784 + 392 + p] + w3 * lw[cj * 784 + 588 + p];
      else if (cj == 10)
        val = (w0 + w1 + w2 + w3) * (1.0f / 196.0f);
    }
  }
  wsf[i] = val;

  if (blockIdx.x == 0) {
    const int u = threadIdx.x;
    if (u < 40) {
      const int d = u / 10, j = u - (u / 10) * 10;
      const float b0 = cb[0], b1 = cb[1], b2 = cb[2], b3 = cb[3];
      float s = 0.f;
#pragma unroll 7
      for (int q = d; q < 196; q += 4)
        s += b0 * lw[j * 784 + q]       + b1 * lw[j * 784 + 196 + q] +
             b2 * lw[j * 784 + 392 + q] + b3 * lw[j * 784 + 588 + q];
      wsf[CST_F + u] = s;
    } else if (u == 40) {
      wsf[A_F] = (cb[0] + cb[1] + cb[2] + cb[3]) * 0.25f;
    }
  }
}

__global__ __launch_bounds__(512)
__attribute__((amdgpu_waves_per_eu(2, 2))) void qsac_main(
    const float* __restrict__ x, const float* __restrict__ wsf,
    const float* __restrict__ lin_b, float* __restrict__ out) {
  // B in LDS: 75 chunks (t*3+nt) x {hi 1KB, lo 1KB} = 153,600 B.
  // Chunk c: hi at byte c*2048 + lane*16, lo at +1024. (160KB limit: ok.)
  __shared__ unsigned int smemu[38400];

  const int tid = threadIdx.x;
  const int lane = tid & 63;
  const int wid = __builtin_amdgcn_readfirstlane(tid >> 6);  // 0..7
  const int nn = lane & 15, kb = lane >> 4;
  const int sbase = blockIdx.x * 128 + wid * 16;
  const float* xrow = x + (size_t)(sbase + nn) * 784;

  // ---- B staging: ws f32 (fragment-major) -> LDS bf16 hi/lo. 4800 jobs;
  // job j: floats [8j,8j+8) -> chunk c=j>>6, lane ln=j&63 (= this lane:
  // j = tid + r*512 -> j&63 == lane). Coalesced reads, conflict-free writes.
#pragma unroll
  for (int r = 0; r < 10; ++r) {
    const int j = tid + r * 512;
    if (j < 4800) {
      const float4 f0 = *(const float4*)(wsf + j * 8);
      const float4 f1 = *(const float4*)(wsf + j * 8 + 4);
      const float v[8] = {f0.x, f0.y, f0.z, f0.w, f1.x, f1.y, f1.z, f1.w};
      unsigned short h[8], l[8];
#pragma unroll
      for (int e = 0; e < 8; ++e) {
        h[e] = f2bf(v[e]);
        l[e] = f2bf(v[e] - bf2f(h[e]));
      }
      uint4v hi, lo;
      hi.x = (unsigned)h[0] | ((unsigned)h[1] << 16);
      hi.y = (unsigned)h[2] | ((unsigned)h[3] << 16);
      hi.z = (unsigned)h[4] | ((unsigned)h[5] << 16);
      hi.w = (unsigned)h[6] | ((unsigned)h[7] << 16);
      lo.x = (unsigned)l[0] | ((unsigned)l[1] << 16);
      lo.y = (unsigned)l[2] | ((unsigned)l[3] << 16);
      lo.z = (unsigned)l[4] | ((unsigned)l[5] << 16);
      lo.w = (unsigned)l[6] | ((unsigned)l[7] << 16);
      const int c = j >> 6;
      *(uint4v*)(smemu + c * 512 + lane * 4) = hi;
      *(uint4v*)(smemu + c * 512 + 256 + lane * 4) = lo;
    }
  }
  __syncthreads();

  f32x4 acc[3];
#pragma unroll
  for (int nt = 0; nt < 3; ++nt) acc[nt] = (f32x4){0.f, 0.f, 0.f, 0.f};

  auto ldA = [&](int t, float4& a, float4& b) {
    const int ka = t * 32 + kb * 8;
    const int kc = (ka < 784) ? ka : 0;  // clamped tail; B rows >=784 are 0
    a = *(const float4*)(xrow + kc);
    b = *(const float4*)(xrow + kc + 4);
  };
  auto ldB = [&](int t, BU (&bh)[3], BU (&bl)[3]) {
    const unsigned int* bb = smemu + t * 1536 + lane * 4;  // t*6144 B
#pragma unroll
    for (int nt = 0; nt < 3; ++nt) {
      bh[nt].u = *(const uint4v*)(bb + nt * 512);
      bl[nt].u = *(const uint4v*)(bb + nt * 512 + 256);
    }
  };
  auto domfma = [&](const float4& a, const float4& b2, BU (&bh)[3], BU (&bl)[3]) {
    const float v[8] = {a.x, a.y, a.z, a.w, b2.x, b2.y, b2.z, b2.w};
    bf16x8 Ah, Al;
#pragma unroll
    for (int e = 0; e < 8; ++e) {
      const unsigned short hh = f2bf(v[e]);
      Ah[e] = (short)hh;
      Al[e] = (short)f2bf(v[e] - bf2f(hh));
    }
#pragma unroll
    for (int nt = 0; nt < 3; ++nt) {
      acc[nt] = __builtin_amdgcn_mfma_f32_16x16x32_bf16(Ah, bh[nt].b, acc[nt], 0, 0, 0);
      acc[nt] = __builtin_amdgcn_mfma_f32_16x16x32_bf16(Al, bh[nt].b, acc[nt], 0, 0, 0);
      acc[nt] = __builtin_amdgcn_mfma_f32_16x16x32_bf16(Ah, bl[nt].b, acc[nt], 0, 0, 0);
    }
  };

  // Depth-1 ping-pong prefetch for A (global) and B (LDS); no barriers.
  float4 xa0, xb0, xa1, xb1;
  BU bh0[3], bl0[3], bh1[3], bl1[3];
  ldA(0, xa0, xb0);
  ldB(0, bh0, bl0);
#pragma unroll 1
  for (int tt = 0; tt < 12; ++tt) {
    ldA(2 * tt + 1, xa1, xb1);
    ldB(2 * tt + 1, bh1, bl1);
    domfma(xa0, xb0, bh0, bl0);           // t = 2tt
    ldA(2 * tt + 2, xa0, xb0);
    ldB(2 * tt + 2, bh0, bl0);
    domfma(xa1, xb1, bh1, bl1);           // t = 2tt+1
  }
  domfma(xa0, xb0, bh0, bl0);             // t = 24

  // ---- epilogue: overlay per-wave C exchange into (now dead) B region ----
  __syncthreads();  // all waves past the loop -> B truly dead
  float* cx = (float*)smemu + wid * (16 * 52);
#pragma unroll
  for (int nt = 0; nt < 3; ++nt)
#pragma unroll
    for (int rg = 0; rg < 4; ++rg)
      cx[(kb * 4 + rg) * 52 + nt * 16 + nn] = acc[nt][rg];
  __builtin_amdgcn_wave_barrier();  // same-wave LDS pipe is in-order

  if (lane < 16) {
    float Y[48];
#pragma unroll
    for (int q = 0; q < 12; ++q) {
      const float4 t4 = *(const float4*)&cx[lane * 52 + q * 4];
      Y[q * 4 + 0] = t4.x; Y[q * 4 + 1] = t4.y;
      Y[q * 4 + 2] = t4.z; Y[q * 4 + 3] = t4.w;
    }
    const float a = wsf[A_F];
    float M[4];
#pragma unroll
    for (int d = 0; d < 4; ++d) M[d] = a + Y[d * 12 + 10];
    float logits[10];
#pragma unroll
    for (int j = 0; j < 10; ++j) {
      float vv = lin_b[j];
#pragma unroll
      for (int d = 0; d < 4; ++d)
        vv += M[d] * (wsf[CST_F + d * 10 + j] + Y[d * 12 + j]);
      logits[j] = vv;
    }
    float mx = logits[0];
#pragma unroll
    for (int j = 1; j < 10; ++j) mx = fmaxf(mx, logits[j]);
    float se = 0.f;
#pragma unroll
    for (int j = 0; j < 10; ++j) se += __expf(logits[j] - mx);
    const float lse = mx + __logf(se);
    float* op = out + (size_t)(sbase + lane) * 10;
#pragma unroll
    for (int j = 0; j < 10; ++j) op[j] = logits[j] - lse;
  }
}

extern "C" void kernel_launch(void* const* d_in, const int* in_sizes, int n_in,
                              void* d_out, int out_size, void* d_ws, size_t ws_size,
                              hipStream_t stream) {
  (void)n_in; (void)ws_size; (void)out_size;
  const float* x = (const float*)d_in[0];
  const float* conv_w = (const float*)d_in[1];
  const float* conv_b = (const float*)d_in[2];
  // d_in[3]/d_in[4] (rotation/entangle) are dead: softmax over length-1 == 1.
  const float* lin_w = (const float*)d_in[5];
  const float* lin_b = (const float*)d_in[6];
  float* out = (float*)d_out;
  float* wsf = (float*)d_ws;

  hipLaunchKernelGGL(qsac_prep, dim3(150), dim3(256), 0, stream,
                     conv_w, conv_b, lin_w, wsf);

  const int B = in_sizes[0] / 784;  // 32768
  const int nblk = B / 128;         // 256 blocks x 512 threads (1 block/CU)
  hipLaunchKernelGGL(qsac_main, dim3(nblk), dim3(512), 0, stream,
                     x, wsf, lin_b, out);
}

// Round 14
// 30.976 us; speedup vs baseline: 1.9770x; 1.0096x over previous
//
#include <hip/hip_runtime.h>

// QuanvolutionSelfAttentionClassifier on MI355X — round 14: deep A-prefetch.
//
// Algebra (verified R1-R13): softmax over length-1 axis == 1 ->
// attn_weights == mean_embeds (rotation/entangle dead). l = c*196+p ->
// d = p&3; pixel (r,cc): d = (2*((r>>1)&1) + (cc>>1)) & 3.
//   logits[j] = lin_b[j] + sum_d M[d]*(cst[d][j] + T[d][j])
//   M[d] = a + sum_pix x*gm,  T[d][j] = sum_{pix in d} x*G[pix][j]
// Y = X·G via mfma_f32_16x16x32_bf16, split-bf16 hi/lo (AhBh+AlBh+AhBl),
// col = d*12+j; symmetric A/B k-placement; C layout col=lane&15,
// row=(lane>>4)*4+reg — numerics verified 3x (R11/R12/R13, absmax 0.0156).
//
// R13 confirmed the TA/L1 model (B->LDS: 44->31us). Remaining gap to the
// ~17us stream floor: A-loads prefetched only depth-1 (~200cy work/iter vs
// ~300-900cy latency, 2 waves/SIMD). v14:
//  1. depth-4 A-prefetch ring in NAMED registers (static indexing).
//  2. prep emits the bf16 hi/lo B-image byte-identical to the LDS layout ->
//     staging is a pure global_load_lds 16B copy (no VALU), wave-uniform
//     dest bases (HW adds lane*16 — m104 contract).
//  3. structure/epilogue otherwise byte-identical to R13.

typedef __attribute__((ext_vector_type(8))) short bf16x8;
typedef __attribute__((ext_vector_type(4))) float f32x4;
typedef __attribute__((ext_vector_type(4))) unsigned int uint4v;

union BU { uint4v u; bf16x8 b; };

__device__ __forceinline__ unsigned short f2bf(float f) {
  unsigned u = __float_as_uint(f);
  unsigned r = u + 0x7FFFu + ((u >> 16) & 1u);
  return (unsigned short)(r >> 16);
}
__device__ __forceinline__ float bf2f(unsigned short h) {
  return __uint_as_float((unsigned)h << 16);
}

#define CST_F 38400   // float idx in ws (after 76800 shorts): cst[40]
#define A_F   38440   // float idx: a

// prep: B-image bf16 hi/lo, BYTE-IDENTICAL to the main kernel's LDS layout.
// i -> e=i&7, ln=(i>>3)&63, c=i>>9 (c = t*3+nt); col=(c%3)*16+(ln&15),
// k=(c/3)*32+(ln>>4)*8+e. Chunk c: hi shorts [c*1024 + ln*8 + e],
// lo at +512 shorts.
__global__ void qsac_prep(const float* __restrict__ cw, const float* __restrict__ cb,
                          const float* __restrict__ lw, float* __restrict__ wsf) {
  unsigned short* gt = (unsigned short*)wsf;
  const int i = blockIdx.x * 256 + threadIdx.x;  // 150 x 256 = 38400
  const int e = i & 7, ln = (i >> 3) & 63, c = i >> 9;
  const int t = c / 3, nt = c - t * 3;
  const int col = nt * 16 + (ln & 15);
  const int k = t * 32 + (ln >> 4) * 8 + e;
  float val = 0.f;
  if (k < 784) {
    const int r = k / 28, cc = k - r * 28;
    const int kh = r & 1, kw = cc & 1;
    const int p = (r >> 1) * 14 + (cc >> 1);
    const int dpix = (2 * ((r >> 1) & 1) + (cc >> 1)) & 3;
    const int cd = col / 12, cj = col - cd * 12;
    if (cd == dpix) {
      const float w0 = cw[(kh << 1) + kw],     w1 = cw[4 + (kh << 1) + kw],
                  w2 = cw[8 + (kh << 1) + kw], w3 = cw[12 + (kh << 1) + kw];
      if (cj < 10)
        val = w0 * lw[cj * 784 + p]       + w1 * lw[cj * 784 + 196 + p] +
              w2 * lw[cj * 784 + 392 + p] + w3 * lw[cj * 784 + 588 + p];
      else if (cj == 10)
        val = (w0 + w1 + w2 + w3) * (1.0f / 196.0f);
    }
  }
  const unsigned short hh = f2bf(val);
  gt[c * 1024 + ln * 8 + e] = hh;
  gt[c * 1024 + 512 + ln * 8 + e] = f2bf(val - bf2f(hh));

  if (blockIdx.x == 0) {
    const int u = threadIdx.x;
    if (u < 40) {
      const int d = u / 10, j = u - (u / 10) * 10;
      const float b0 = cb[0], b1 = cb[1], b2 = cb[2], b3 = cb[3];
      float s = 0.f;
#pragma unroll 7
      for (int q = d; q < 196; q += 4)
        s += b0 * lw[j * 784 + q]       + b1 * lw[j * 784 + 196 + q] +
             b2 * lw[j * 784 + 392 + q] + b3 * lw[j * 784 + 588 + q];
      wsf[CST_F + u] = s;
    } else if (u == 40) {
      wsf[A_F] = (cb[0] + cb[1] + cb[2] + cb[3]) * 0.25f;
    }
  }
}

__global__ __launch_bounds__(512)
__attribute__((amdgpu_waves_per_eu(2, 2))) void qsac_main(
    const float* __restrict__ x, const float* __restrict__ wsf,
    const float* __restrict__ lin_b, float* __restrict__ out) {
  // B in LDS: chunk c (=t*3+nt): hi 16B/lane at byte c*2048+lane*16, lo +1024.
  __shared__ unsigned int smemu[38400];  // 153,600 B

  const int tid = threadIdx.x;
  const int lane = tid & 63;
  const int wid = __builtin_amdgcn_readfirstlane(tid >> 6);  // 0..7
  const int nn = lane & 15, kb = lane >> 4;
  const int sbase = blockIdx.x * 128 + wid * 16;
  const float* xrow = x + (size_t)(sbase + nn) * 784;

  // ---- B staging: pure 16B global_load_lds copy of the ws image.
  // 9600 chunks; wave-uniform LDS base (HW adds lane*16).
  {
    const char* wsb = (const char*)wsf;
#pragma unroll
    for (int i = 0; i < 18; ++i) {
      const int cbase = i * 512 + wid * 64;
      __builtin_amdgcn_global_load_lds(
          (const __attribute__((address_space(1))) unsigned int*)
              (wsb + (size_t)(cbase + lane) * 16),
          (__attribute__((address_space(3))) unsigned int*)&smemu[cbase * 4],
          16, 0, 0);
    }
    if (wid < 6) {
      const int cbase = 9216 + wid * 64;
      __builtin_amdgcn_global_load_lds(
          (const __attribute__((address_space(1))) unsigned int*)
              (wsb + (size_t)(cbase + lane) * 16),
          (__attribute__((address_space(3))) unsigned int*)&smemu[cbase * 4],
          16, 0, 0);
    }
  }
  __syncthreads();  // drains vmcnt -> B image complete

  f32x4 acc[3];
#pragma unroll
  for (int nt = 0; nt < 3; ++nt) acc[nt] = (f32x4){0.f, 0.f, 0.f, 0.f};

  auto tile = [&](const float4& a, const float4& b2, int t) {
    BU bh[3], bl[3];
    const unsigned int* bb = smemu + t * 1536 + lane * 4;
#pragma unroll
    for (int nt = 0; nt < 3; ++nt) {
      bh[nt].u = *(const uint4v*)(bb + nt * 512);
      bl[nt].u = *(const uint4v*)(bb + nt * 512 + 256);
    }
    const float v[8] = {a.x, a.y, a.z, a.w, b2.x, b2.y, b2.z, b2.w};
    bf16x8 Ah, Al;
#pragma unroll
    for (int e = 0; e < 8; ++e) {
      const unsigned short hh = f2bf(v[e]);
      Ah[e] = (short)hh;
      Al[e] = (short)f2bf(v[e] - bf2f(hh));
    }
#pragma unroll
    for (int nt = 0; nt < 3; ++nt) {
      acc[nt] = __builtin_amdgcn_mfma_f32_16x16x32_bf16(Ah, bh[nt].b, acc[nt], 0, 0, 0);
      acc[nt] = __builtin_amdgcn_mfma_f32_16x16x32_bf16(Al, bh[nt].b, acc[nt], 0, 0, 0);
      acc[nt] = __builtin_amdgcn_mfma_f32_16x16x32_bf16(Ah, bl[nt].b, acc[nt], 0, 0, 0);
    }
  };

#define LD_A(PA, PB, T)                                                       \
  {                                                                           \
    const int ka = (T)*32 + kb * 8;                                           \
    const int kc = (ka < 784) ? ka : 0; /* tail: B rows >=784 are zero */     \
    PA = *(const float4*)(xrow + kc);                                         \
    PB = *(const float4*)(xrow + kc + 4);                                     \
  }

  // Depth-4 A-prefetch ring in named registers (static indexing).
  float4 a0, b0, a1, b1, a2, b2, a3, b3;
  LD_A(a0, b0, 0) LD_A(a1, b1, 1) LD_A(a2, b2, 2) LD_A(a3, b3, 3)

#pragma unroll 1
  for (int it = 0; it < 6; ++it) {
    const int t = it * 4;
    tile(a0, b0, t + 0); if (t + 4 < 25) LD_A(a0, b0, t + 4)
    tile(a1, b1, t + 1); if (t + 5 < 25) LD_A(a1, b1, t + 5)
    tile(a2, b2, t + 2); if (t + 6 < 25) LD_A(a2, b2, t + 6)
    tile(a3, b3, t + 3); if (t + 7 < 25) LD_A(a3, b3, t + 7)
  }
  tile(a0, b0, 24);

  // ---- epilogue (R13-verified): overlay C exchange into dead B region ----
  __syncthreads();  // all waves past the loop -> B truly dead
  float* cx = (float*)smemu + wid * (16 * 52);
#pragma unroll
  for (int nt = 0; nt < 3; ++nt)
#pragma unroll
    for (int rg = 0; rg < 4; ++rg)
      cx[(kb * 4 + rg) * 52 + nt * 16 + nn] = acc[nt][rg];
  __builtin_amdgcn_wave_barrier();  // same-wave LDS pipe is in-order

  if (lane < 16) {
    float Y[48];
#pragma unroll
    for (int q = 0; q < 12; ++q) {
      const float4 t4 = *(const float4*)&cx[lane * 52 + q * 4];
      Y[q * 4 + 0] = t4.x; Y[q * 4 + 1] = t4.y;
      Y[q * 4 + 2] = t4.z; Y[q * 4 + 3] = t4.w;
    }
    const float a = wsf[A_F];
    float M[4];
#pragma unroll
    for (int d = 0; d < 4; ++d) M[d] = a + Y[d * 12 + 10];
    float logits[10];
#pragma unroll
    for (int j = 0; j < 10; ++j) {
      float vv = lin_b[j];
#pragma unroll
      for (int d = 0; d < 4; ++d)
        vv += M[d] * (wsf[CST_F + d * 10 + j] + Y[d * 12 + j]);
      logits[j] = vv;
    }
    float mx = logits[0];
#pragma unroll
    for (int j = 1; j < 10; ++j) mx = fmaxf(mx, logits[j]);
    float se = 0.f;
#pragma unroll
    for (int j = 0; j < 10; ++j) se += __expf(logits[j] - mx);
    const float lse = mx + __logf(se);
    float* op = out + (size_t)(sbase + lane) * 10;
#pragma unroll
    for (int j = 0; j < 10; ++j) op[j] = logits[j] - lse;
  }
#undef LD_A
}

extern "C" void kernel_launch(void* const* d_in, const int* in_sizes, int n_in,
                              void* d_out, int out_size, void* d_ws, size_t ws_size,
                              hipStream_t stream) {
  (void)n_in; (void)ws_size; (void)out_size;
  const float* x = (const float*)d_in[0];
  const float* conv_w = (const float*)d_in[1];
  const float* conv_b = (const float*)d_in[2];
  // d_in[3]/d_in[4] (rotation/entangle) are dead: softmax over length-1 == 1.
  const float* lin_w = (const float*)d_in[5];
  const float* lin_b = (const float*)d_in[6];
  float* out = (float*)d_out;
  float* wsf = (float*)d_ws;

  hipLaunchKernelGGL(qsac_prep, dim3(150), dim3(256), 0, stream,
                     conv_w, conv_b, lin_w, wsf);

  const int B = in_sizes[0] / 784;  // 32768
  const int nblk = B / 128;         // 256 blocks x 512 threads (1 block/CU)
  hipLaunchKernelGGL(qsac_main, dim3(nblk), dim3(512), 0, stream,
                     x, wsf, lin_b, out);
}